// Round 1
// 1103.661 us; speedup vs baseline: 1.0047x; 1.0047x over previous
//
#include <hip/hip_runtime.h>

#define NB 512
#define NT 256
#define NI 32
#define NH 128
#define NG 512

typedef __attribute__((ext_vector_type(8))) short bf16x8;
typedef __attribute__((ext_vector_type(4))) float f32x4;

__device__ __forceinline__ float fsig(float x) { return 1.0f / (1.0f + __expf(-x)); }
__device__ __forceinline__ float ftanh(float x) {
    float ax = fabsf(x);
    float e  = __expf(-2.0f * ax);
    float t  = (1.0f - e) / (1.0f + e);
    return copysignf(t, x);
}
__device__ __forceinline__ unsigned short f2bf_rne(float f) {
    unsigned u = __float_as_uint(f);
    return (unsigned short)((u + 0x7FFFu + ((u >> 16) & 1u)) >> 16);
}
__device__ __forceinline__ void split2(float a, float b, unsigned& hi, unsigned& lo) {
    unsigned short ha = f2bf_rne(a), hb = f2bf_rne(b);
    float ra = a - __uint_as_float((unsigned)ha << 16);
    float rb = b - __uint_as_float((unsigned)hb << 16);
    hi = (unsigned)ha | ((unsigned)hb << 16);
    lo = (unsigned)f2bf_rne(ra) | ((unsigned)f2bf_rne(rb) << 16);
}
__device__ __forceinline__ bf16x8 u4bf(uint4 u) {
    union { uint4 u; bf16x8 v; } c; c.u = u; return c.v;
}
__device__ __forceinline__ unsigned packh(float h) {
    unsigned short hi = f2bf_rne(h);
    float r = h - __uint_as_float((unsigned)hi << 16);
    return (unsigned)hi | ((unsigned)f2bf_rne(r) << 16);
}
#define MFMA16(accv, av, bv) \
    accv = __builtin_amdgcn_mfma_f32_16x16x32_bf16(av, bv, accv, 0, 0, 0)

// LDS-only barrier: orders ds ops across waves WITHOUT draining vmcnt.
__device__ __forceinline__ void lds_barrier() {
    asm volatile("s_waitcnt lgkmcnt(0)\n\ts_barrier" ::: "memory");
}

// ---------------------------------------------------------------------------
// Paired MFMA LSTM recurrence: 64 blocks x 512 threads, ZERO inter-role comms.
//   role 0 (blk  0-31): layer-0 recurrence, chunk i   (reads xg0, writes h0buf)
//   role 1 (blk 32-63): layer-1 recurrence, chunk i-1 (reads xg1)
// R15 critical-path fixes (per-step was ~6600 cyc with all pipes <30% busy):
//  - Wl (lo-half weights) was a per-lane LDS spill: 128 ds_read_b128/step per
//    block (~1700 cyc of LDS pipe + ~120cyc latency ahead of each dependent
//    MFMA). VGPR_Count was only 88 of the 256 budget at this occupancy
//    (512thr, 1 blk/CU) -> keep lo-half in registers (wl[4][4], +64 VGPR).
//    LDS shrinks 147456 -> 16384 B; LDS now holds only the h exchange.
//  - xg loads were issued and consumed in the SAME step (vmcnt stall after
//    the MFMA chain). Double-buffer xga/xgb one step ahead (2-step unrolled
//    loop keeps all array indexing compile-time static; +16 VGPR).
// ---------------------------------------------------------------------------
__global__ __launch_bounds__(512, 1)
void recur_pair(const float* __restrict__ xg0,   // [NB*Tc][NG] rows b*Tc+tl
                const float* __restrict__ xg1,
                const float* __restrict__ w_hh0,
                const float* __restrict__ w_hh1,
                float* __restrict__ h0buf,       // role0 hout
                float* __restrict__ h0s, float* __restrict__ c0s,
                float* __restrict__ h1s, float* __restrict__ c1s,
                int Tc, int doA, int doB, int firstA, int firstB)
{
    __shared__ __align__(16) unsigned WA[2][4][64][4];        // 8192 B
    __shared__ __align__(16) unsigned WB[2][4][64][4];        // 8192 B

    const int role = blockIdx.x >> 5;
    if (role == 0 && !doA) return;
    if (role == 1 && !doB) return;

    const float* xg    = role ? xg1   : xg0;
    const float* wsrc  = role ? w_hh1 : w_hh0;
    float*       hout  = role ? nullptr : h0buf;
    float*       hs    = role ? h1s : h0s;
    float*       cs    = role ? c1s : c0s;
    const int    first = role ? firstB : firstA;

    const int p    = blockIdx.x & 31;
    const int tid  = threadIdx.x;
    const int wv   = tid >> 6;
    const int lane = tid & 63;
    const int quad = lane >> 4;
    const int ml   = lane & 15;
    const int j    = 16 * wv + ml;

    // h-store coordinates (uniform in r): j -> (q_s, quad_s, d)
    const int q_s    = j >> 5;
    const int quad_s = (j >> 3) & 3;
    const int dd     = j & 3;
    const bool loA   = (j & 7) < 4;

    // ---- stage weights: hi AND lo halves fully in registers ----
    bf16x8 wh[4][4], wl[4][4];
#pragma unroll
    for (int t = 0; t < 4; ++t) {
#pragma unroll
        for (int q = 0; q < 4; ++q) {
            int n = (t * 8 + wv) * 16 + ml;
            const float* s = wsrc + (size_t)n * NH + q * 32 + quad * 8;
            float4 v0 = *(const float4*)s;
            float4 v1 = *(const float4*)(s + 4);
            uint4 H, L;
            split2(v0.x, v0.y, H.x, L.x); split2(v0.z, v0.w, H.y, L.y);
            split2(v1.x, v1.y, H.z, L.z); split2(v1.z, v1.w, H.w, L.w);
            wh[t][q] = u4bf(H);
            wl[t][q] = u4bf(L);
        }
    }

    const size_t rs = (size_t)Tc * NG;
    const size_t rowb0 = ((size_t)(p * 16 + quad * 4) * Tc) * NG + j;

    // xg double-buffer: prefetch step 0 now (hides behind staging + init)
    float xga[4][4], xgb[4][4];
#pragma unroll
    for (int t = 0; t < 4; ++t)
#pragma unroll
        for (int r = 0; r < 4; ++r)
            xga[t][r] = xg[rowb0 + (size_t)r * rs + t * 128];

    // ---- initial c/h ----
    float cr[4];
#pragma unroll
    for (int r = 0; r < 4; ++r) {
        int m = quad * 4 + r;
        float h = 0.f, c = 0.f;
        if (!first) {
            h = hs[(size_t)(p * 16 + m) * NH + j];
            c = cs[(size_t)(p * 16 + m) * NH + j];
        }
        cr[r] = c;
        unsigned pv = packh(h);
        if (loA) WA[0][q_s][quad_s * 16 + m][dd] = pv;
        else     WB[0][q_s][quad_s * 16 + m][dd] = pv;
    }
    __syncthreads();

    auto prefetch = [&](float (&dst)[4][4], int tlx) __attribute__((always_inline)) {
        int tc_ = tlx < Tc ? tlx : Tc - 1;     // clamp: harmless redundant load
        const size_t rowb = rowb0 + (size_t)tc_ * NG;
#pragma unroll
        for (int t = 0; t < 4; ++t)
#pragma unroll
            for (int r = 0; r < 4; ++r)
                dst[t][r] = xg[rowb + (size_t)r * rs + t * 128];
    };

    auto step_body = [&](int TL, int BUF, const float (&xgv)[4][4]) __attribute__((always_inline)) {
        f32x4 acc[4] = {};
#pragma unroll
        for (int q = 0; q < 4; ++q) {
            uint4 wAv = *(const uint4*)&WA[BUF][q][lane][0];   // dense b128
            uint4 wBv = *(const uint4*)&WB[BUF][q][lane][0];   // dense b128
            uint4 AH, AL;
            AH.x = (wAv.x & 0xffffu) | (wAv.y << 16);
            AH.y = (wAv.z & 0xffffu) | (wAv.w << 16);
            AH.z = (wBv.x & 0xffffu) | (wBv.y << 16);
            AH.w = (wBv.z & 0xffffu) | (wBv.w << 16);
            AL.x = (wAv.x >> 16) | (wAv.y & 0xffff0000u);
            AL.y = (wAv.z >> 16) | (wAv.w & 0xffff0000u);
            AL.z = (wBv.x >> 16) | (wBv.y & 0xffff0000u);
            AL.w = (wBv.z >> 16) | (wBv.w & 0xffff0000u);
            bf16x8 ah = u4bf(AH), al = u4bf(AL);
#pragma unroll
            for (int t = 0; t < 4; ++t) {
                MFMA16(acc[t], ah, wh[t][q]);
                MFMA16(acc[t], al, wh[t][q]);
                MFMA16(acc[t], ah, wl[t][q]);
            }
        }

        // in-register gate activation + c/h update
#pragma unroll
        for (int r = 0; r < 4; ++r) {
            float gi = fsig (acc[0][r] + xgv[0][r]);
            float gf = fsig (acc[1][r] + xgv[1][r]);
            float gg = ftanh(acc[2][r] + xgv[2][r]);
            float go = fsig (acc[3][r] + xgv[3][r]);
            cr[r] = gf * cr[r] + gi * gg;
            float hn = go * ftanh(cr[r]);
            int m = quad * 4 + r;
            unsigned pv = packh(hn);
            if (loA) WA[BUF ^ 1][q_s][quad_s * 16 + m][dd] = pv;
            else     WB[BUF ^ 1][q_s][quad_s * 16 + m][dd] = pv;
            if (hout)
                hout[((size_t)(p * 16 + m) * Tc + TL) * NH + j] = hn;
            if (TL == Tc - 1) {
                hs[(size_t)(p * 16 + m) * NH + j] = hn;
                cs[(size_t)(p * 16 + m) * NH + j] = cr[r];
            }
        }
    };

    for (int tl = 0; tl < Tc; tl += 2) {
        prefetch(xgb, tl + 1);          // next step's xg: issued a full step early
        step_body(tl, 0, xga);
        lds_barrier();   // LDS-only: don't drain hout/state global stores
        if (tl + 1 < Tc) {
            prefetch(xga, tl + 2);
            step_body(tl + 1, 1, xgb);
            lds_barrier();
        }
    }
}

// ---------------------------------------------------------------------------
// Split-bf16 MFMA GEMM (R8-verified): C = A @ Bw^T + (bi+bh).
// ---------------------------------------------------------------------------
template<int KP, bool SLICED>
__global__ __launch_bounds__(256)
void gemm_mfma(const float* __restrict__ A,
               const float* __restrict__ Bw,
               const float* __restrict__ bi, const float* __restrict__ bh,
               float* __restrict__ C, int t0, int tcShift)
{
    constexpr int K = KP * 32;
    __shared__ __align__(16) unsigned short Ah[4][128][8], Al[4][128][8];
    __shared__ __align__(16) unsigned short Bh[4][64][8],  Bl[4][64][8];
    const int tid  = threadIdx.x;
    const int n0   = blockIdx.x * 64;
    const int m0   = blockIdx.y * 128;
    const int wv   = tid >> 6;
    const int lane = tid & 63;
    const int quad = lane >> 4, ml = lane & 15;

    f32x4 acc[2][4] = {};
    float bias[4];
#pragma unroll
    for (int nt = 0; nt < 4; ++nt) {
        int n = n0 + nt * 16 + ml;
        bias[nt] = bi[n] + bh[n];
    }

    for (int kp = 0; kp < KP; ++kp) {
        if (kp) __syncthreads();
#pragma unroll
        for (int r = 0; r < 2; ++r) {
            int u = tid + 256 * r;
            int m = u >> 2, ck = u & 3;
            size_t abase;
            if (SLICED) {
                int mg = m0 + m;
                int b  = mg >> tcShift, tl = mg & ((1 << tcShift) - 1);
                abase = ((size_t)b * NT + (t0 + tl)) * K;
            } else {
                abase = (size_t)(m0 + m) * K;
            }
            const float* s = A + abase + kp * 32 + ck * 8;
            float4 v0 = *(const float4*)s;
            float4 v1 = *(const float4*)(s + 4);
            uint4 H, L;
            split2(v0.x, v0.y, H.x, L.x); split2(v0.z, v0.w, H.y, L.y);
            split2(v1.x, v1.y, H.z, L.z); split2(v1.z, v1.w, H.w, L.w);
            *(uint4*)&Ah[ck][m][0] = H;
            *(uint4*)&Al[ck][m][0] = L;
        }
        {
            int n = tid >> 2, ck = tid & 3;
            const float* s = Bw + (size_t)(n0 + n) * K + kp * 32 + ck * 8;
            float4 v0 = *(const float4*)s;
            float4 v1 = *(const float4*)(s + 4);
            uint4 H, L;
            split2(v0.x, v0.y, H.x, L.x); split2(v0.z, v0.w, H.y, L.y);
            split2(v1.x, v1.y, H.z, L.z); split2(v1.z, v1.w, H.w, L.w);
            *(uint4*)&Bh[ck][n][0] = H;
            *(uint4*)&Bl[ck][n][0] = L;
        }
        __syncthreads();

        bf16x8 ah0 = *(const bf16x8*)&Ah[quad][(2 * wv + 0) * 16 + ml][0];
        bf16x8 al0 = *(const bf16x8*)&Al[quad][(2 * wv + 0) * 16 + ml][0];
        bf16x8 ah1 = *(const bf16x8*)&Ah[quad][(2 * wv + 1) * 16 + ml][0];
        bf16x8 al1 = *(const bf16x8*)&Al[quad][(2 * wv + 1) * 16 + ml][0];
#pragma unroll
        for (int nt = 0; nt < 4; ++nt) {
            bf16x8 bhv = *(const bf16x8*)&Bh[quad][nt * 16 + ml][0];
            bf16x8 blv = *(const bf16x8*)&Bl[quad][nt * 16 + ml][0];
            MFMA16(acc[0][nt], ah0, bhv);
            MFMA16(acc[0][nt], ah0, blv);
            MFMA16(acc[0][nt], al0, bhv);
            MFMA16(acc[1][nt], ah1, bhv);
            MFMA16(acc[1][nt], ah1, blv);
            MFMA16(acc[1][nt], al1, bhv);
        }
    }

#pragma unroll
    for (int mt = 0; mt < 2; ++mt)
#pragma unroll
        for (int nt = 0; nt < 4; ++nt)
#pragma unroll
            for (int reg = 0; reg < 4; ++reg) {
                int m = m0 + (2 * wv + mt) * 16 + quad * 4 + reg;
                int n = n0 + nt * 16 + ml;
                C[(size_t)m * NG + n] = acc[mt][nt][reg] + bias[nt];
            }
}

// ---------------------------------------------------------------------------
// out[b] = fc2_w . relu(fc1_w @ h1_last[b] + fc1_b) + fc2_b
// ---------------------------------------------------------------------------
__global__ void fc_head(const float* __restrict__ h1,
                        const float* __restrict__ fc1w, const float* __restrict__ fc1b,
                        const float* __restrict__ fc2w, const float* __restrict__ fc2b,
                        float* __restrict__ out)
{
    int b = blockIdx.x, j = threadIdx.x;
    const float4* wr = (const float4*)(fc1w + (size_t)j * NH);
    const float4* hv = (const float4*)(h1 + (size_t)b * NH);
    float acc = fc1b[j];
#pragma unroll
    for (int q = 0; q < 32; ++q) {
        float4 w = wr[q], h = hv[q];
        acc += w.x * h.x + w.y * h.y + w.z * h.z + w.w * h.w;
    }
    float z = fmaxf(acc, 0.0f);
    float p = fc2w[j] * z;
#pragma unroll
    for (int off = 32; off > 0; off >>= 1) p += __shfl_down(p, off);
    if (j == 0) out[b] = p + fc2b[0];
}

extern "C" void kernel_launch(void* const* d_in, const int* in_sizes, int n_in,
                              void* d_out, int out_size, void* d_ws, size_t ws_size,
                              hipStream_t stream)
{
    const float* x     = (const float*)d_in[0];
    const float* w_ih0 = (const float*)d_in[1];
    const float* w_hh0 = (const float*)d_in[2];
    const float* b_ih0 = (const float*)d_in[3];
    const float* b_hh0 = (const float*)d_in[4];
    const float* w_ih1 = (const float*)d_in[5];
    const float* w_hh1 = (const float*)d_in[6];
    const float* b_ih1 = (const float*)d_in[7];
    const float* b_hh1 = (const float*)d_in[8];
    const float* fc1w  = (const float*)d_in[9];
    const float* fc1b  = (const float*)d_in[10];
    const float* fc2w  = (const float*)d_in[11];
    const float* fc2b  = (const float*)d_in[12];
    float* out = (float*)d_out;
    float* ws  = (float*)d_ws;

    // xg0 + xg1 + h0 + 4 state arrays (Tc=64 at the known ws budget)
    int Tc = 1;
    for (int cand = 256; cand >= 1; cand >>= 1) {
        size_t need = 4ull * ((size_t)NB * cand * (2 * NG + NH) + 4ull * NB * NH);
        if (need <= ws_size) { Tc = cand; break; }
    }
    int tcShift = __builtin_ctz((unsigned)Tc);

    size_t o_xg0 = 0;
    size_t o_xg1 = o_xg0 + (size_t)NB * Tc * NG;
    size_t o_h0  = o_xg1 + (size_t)NB * Tc * NG;
    size_t o_h0s = o_h0  + (size_t)NB * Tc * NH;
    size_t o_c0s = o_h0s + (size_t)NB * NH;
    size_t o_h1s = o_c0s + (size_t)NB * NH;
    size_t o_c1s = o_h1s + (size_t)NB * NH;

    const int M = NB * Tc;
    const int nchunk = NT / Tc;

    // xg0 for chunk 0
    gemm_mfma<1, true><<<dim3(8, M / 128), 256, 0, stream>>>(
        x, w_ih0, b_ih0, b_hh0, ws + o_xg0, 0, tcShift);

    for (int i = 0; i <= nchunk; ++i) {
        int doA = (i < nchunk), doB = (i >= 1);
        recur_pair<<<64, 512, 0, stream>>>(
            ws + o_xg0, ws + o_xg1, w_hh0, w_hh1, ws + o_h0,
            ws + o_h0s, ws + o_c0s, ws + o_h1s, ws + o_c1s,
            Tc, doA, doB, i == 0, i == 1);
        if (i < nchunk)        // xg1 for chunk i (consumed by role1 next iter)
            gemm_mfma<4, false><<<dim3(8, M / 128), 256, 0, stream>>>(
                ws + o_h0, w_ih1, b_ih1, b_hh1, ws + o_xg1, 0, 0);
        if (i + 1 < nchunk)    // xg0 for chunk i+1 (consumed by role0 next iter)
            gemm_mfma<1, true><<<dim3(8, M / 128), 256, 0, stream>>>(
                x, w_ih0, b_ih0, b_hh0, ws + o_xg0, (i + 1) * Tc, tcShift);
    }
    fc_head<<<NB, 64, 0, stream>>>(ws + o_h1s, fc1w, fc1b, fc2w, fc2b, out);
}

// Round 2
// 825.590 us; speedup vs baseline: 1.3432x; 1.3368x over previous
//
#include <hip/hip_runtime.h>

#define NB 512
#define NT 256
#define NI 32
#define NH 128
#define NG 512

typedef __attribute__((ext_vector_type(8))) short bf16x8;
typedef __attribute__((ext_vector_type(4))) float f32x4;

// R16: rcp-based activations (v_rcp_f32 is <=1 ulp; the full-precision div
// sequence was ~12 VALU ops x 20 divides/thread/step -> dominant VALU cost).
// Both forms are overflow-safe: exp->inf => rcp->0 => correct saturation.
__device__ __forceinline__ float fsig(float x) {
    return __builtin_amdgcn_rcpf(1.0f + __expf(-x));
}
__device__ __forceinline__ float ftanh(float x) {
    float e = __expf(-2.0f * x);
    return 2.0f * __builtin_amdgcn_rcpf(1.0f + e) - 1.0f;
}
__device__ __forceinline__ unsigned short f2bf_rne(float f) {
    unsigned u = __float_as_uint(f);
    return (unsigned short)((u + 0x7FFFu + ((u >> 16) & 1u)) >> 16);
}
__device__ __forceinline__ void split2(float a, float b, unsigned& hi, unsigned& lo) {
    unsigned short ha = f2bf_rne(a), hb = f2bf_rne(b);
    float ra = a - __uint_as_float((unsigned)ha << 16);
    float rb = b - __uint_as_float((unsigned)hb << 16);
    hi = (unsigned)ha | ((unsigned)hb << 16);
    lo = (unsigned)f2bf_rne(ra) | ((unsigned)f2bf_rne(rb) << 16);
}
__device__ __forceinline__ bf16x8 u4bf(uint4 u) {
    union { uint4 u; bf16x8 v; } c; c.u = u; return c.v;
}
#define MFMA16(accv, av, bv) \
    accv = __builtin_amdgcn_mfma_f32_16x16x32_bf16(av, bv, accv, 0, 0, 0)

// LDS-only barrier: orders ds ops across waves WITHOUT draining vmcnt.
__device__ __forceinline__ void lds_barrier() {
    asm volatile("s_waitcnt lgkmcnt(0)\n\ts_barrier" ::: "memory");
}

// ---------------------------------------------------------------------------
// Paired MFMA LSTM recurrence: 64 blocks x 512 threads, ZERO inter-role comms.
//   role 0 (blk  0-31): layer-0 recurrence, chunk i   (reads xg0, writes h0buf)
//   role 1 (blk 32-63): layer-1 recurrence, chunk i-1 (reads xg1)
// R16 theory: per-active-CU counters (64/256 CUs busy -> x4 the reported
// numbers) show VALUBusy~67% + MfmaUtil~23% => the step is VALU-ISSUE-bound.
// This revision cuts VALU ~3x:
//  - activations use v_rcp_f32 instead of IEEE divide sequences (20/thread/step)
//  - h exchange: hi/lo stored as SEPARATE bf16 [16][128] LDS tiles, XOR-swizzled
//    (byte ^= (m&7)<<4). Reader's ds_read_b128 at row m=ml IS the MFMA A-frag:
//    the 96-op/step AH/AL repack and the per-lane loA branch are gone.
//    Swizzle: raw [16][128]x2B read b128 along a row = 16-way bank conflict;
//    swizzled -> 2-way (free). Write side (ds_write_b16 scatter) is 4-way on a
//    2-cyc store = noise.
//  - all LDS/global offsets precomputed outside the step loop.
// ---------------------------------------------------------------------------
__global__ __launch_bounds__(512, 1)
void recur_pair(const float* __restrict__ xg0,   // [NB*Tc][NG] rows b*Tc+tl
                const float* __restrict__ xg1,
                const float* __restrict__ w_hh0,
                const float* __restrict__ w_hh1,
                float* __restrict__ h0buf,       // role0 hout
                float* __restrict__ h0s, float* __restrict__ c0s,
                float* __restrict__ h1s, float* __restrict__ c1s,
                int Tc, int doA, int doB, int firstA, int firstB)
{
    __shared__ __align__(16) unsigned short Hh[2][16][128];   // 8192 B
    __shared__ __align__(16) unsigned short Hl[2][16][128];   // 8192 B

    const int role = blockIdx.x >> 5;
    if (role == 0 && !doA) return;
    if (role == 1 && !doB) return;

    const float* xg    = role ? xg1   : xg0;
    const float* wsrc  = role ? w_hh1 : w_hh0;
    float*       hout  = role ? nullptr : h0buf;
    float*       hs    = role ? h1s : h0s;
    float*       cs    = role ? c1s : c0s;
    const int    first = role ? firstB : firstA;

    const int p    = blockIdx.x & 31;
    const int tid  = threadIdx.x;
    const int wv   = tid >> 6;
    const int lane = tid & 63;
    const int quad = lane >> 4;
    const int ml   = lane & 15;
    const int j    = 16 * wv + ml;

    // ---- stage weights: hi AND lo halves fully in registers ----
    bf16x8 wh[4][4], wl[4][4];
#pragma unroll
    for (int t = 0; t < 4; ++t) {
#pragma unroll
        for (int q = 0; q < 4; ++q) {
            int n = (t * 8 + wv) * 16 + ml;
            const float* s = wsrc + (size_t)n * NH + q * 32 + quad * 8;
            float4 v0 = *(const float4*)s;
            float4 v1 = *(const float4*)(s + 4);
            uint4 H, L;
            split2(v0.x, v0.y, H.x, L.x); split2(v0.z, v0.w, H.y, L.y);
            split2(v1.x, v1.y, H.z, L.z); split2(v1.z, v1.w, H.w, L.w);
            wh[t][q] = u4bf(H);
            wl[t][q] = u4bf(L);
        }
    }

    // ---- precomputed per-thread offsets ----
    // read: A-frag for q-slice = Hh[m=ml][k = q*32 + quad*8 .. +7] (bytes)
    int ro[4];
#pragma unroll
    for (int q = 0; q < 4; ++q)
        ro[q] = ((ml * 256 + q * 64 + quad * 16) ^ ((ml & 7) << 4));
    // write: h(m = quad*4+r, j) scatter (bytes)
    int wo[4];
    size_t hb_r[4], sb_r[4];
#pragma unroll
    for (int r = 0; r < 4; ++r) {
        int m = quad * 4 + r;
        wo[r]   = ((m * 256 + j * 2) ^ ((m & 7) << 4));
        hb_r[r] = (size_t)(p * 16 + m) * Tc * NH + j;
        sb_r[r] = (size_t)(p * 16 + m) * NH + j;
    }

    const size_t rs = (size_t)Tc * NG;
    const size_t rowb0 = ((size_t)(p * 16 + quad * 4) * Tc) * NG + j;

    // xg double-buffer: prefetch step 0 now (hides behind staging + init)
    float xga[4][4], xgb[4][4];
#pragma unroll
    for (int t = 0; t < 4; ++t)
#pragma unroll
        for (int r = 0; r < 4; ++r)
            xga[t][r] = xg[rowb0 + (size_t)r * rs + t * 128];

    // ---- initial c/h ----
    float cr[4];
#pragma unroll
    for (int r = 0; r < 4; ++r) {
        float h = 0.f, c = 0.f;
        if (!first) {
            h = hs[sb_r[r]];
            c = cs[sb_r[r]];
        }
        cr[r] = c;
        unsigned short hi = f2bf_rne(h);
        float res = h - __uint_as_float((unsigned)hi << 16);
        unsigned short lo = f2bf_rne(res);
        *(unsigned short*)((char*)&Hh[0][0][0] + wo[r]) = hi;
        *(unsigned short*)((char*)&Hl[0][0][0] + wo[r]) = lo;
    }
    __syncthreads();

    auto prefetch = [&](float (&dst)[4][4], int tlx) __attribute__((always_inline)) {
        int tc_ = tlx < Tc ? tlx : Tc - 1;     // clamp: harmless redundant load
        const size_t rowb = rowb0 + (size_t)tc_ * NG;
#pragma unroll
        for (int t = 0; t < 4; ++t)
#pragma unroll
            for (int r = 0; r < 4; ++r)
                dst[t][r] = xg[rowb + (size_t)r * rs + t * 128];
    };

    auto step_body = [&](int TL, int BUF, const float (&xgv)[4][4]) __attribute__((always_inline)) {
        const char* hb = (const char*)&Hh[BUF][0][0];
        const char* lb = (const char*)&Hl[BUF][0][0];
        char* hbn = (char*)&Hh[BUF ^ 1][0][0];
        char* lbn = (char*)&Hl[BUF ^ 1][0][0];

        f32x4 acc[4] = {};
#pragma unroll
        for (int q = 0; q < 4; ++q) {
            bf16x8 ah = *(const bf16x8*)(hb + ro[q]);   // swizzled dense b128
            bf16x8 al = *(const bf16x8*)(lb + ro[q]);
#pragma unroll
            for (int t = 0; t < 4; ++t) {
                MFMA16(acc[t], ah, wh[t][q]);
                MFMA16(acc[t], al, wh[t][q]);
                MFMA16(acc[t], ah, wl[t][q]);
            }
        }

        // in-register gate activation + c/h update
#pragma unroll
        for (int r = 0; r < 4; ++r) {
            float gi = fsig (acc[0][r] + xgv[0][r]);
            float gf = fsig (acc[1][r] + xgv[1][r]);
            float gg = ftanh(acc[2][r] + xgv[2][r]);
            float go = fsig (acc[3][r] + xgv[3][r]);
            cr[r] = gf * cr[r] + gi * gg;
            float hn = go * ftanh(cr[r]);
            unsigned short hi = f2bf_rne(hn);
            float res = hn - __uint_as_float((unsigned)hi << 16);
            unsigned short lo = f2bf_rne(res);
            *(unsigned short*)(hbn + wo[r]) = hi;
            *(unsigned short*)(lbn + wo[r]) = lo;
            if (hout)
                hout[hb_r[r] + (size_t)TL * NH] = hn;
            if (TL == Tc - 1) {
                hs[sb_r[r]] = hn;
                cs[sb_r[r]] = cr[r];
            }
        }
    };

    for (int tl = 0; tl < Tc; tl += 2) {
        prefetch(xgb, tl + 1);          // next step's xg: issued a full step early
        step_body(tl, 0, xga);
        lds_barrier();   // LDS-only: don't drain hout/state global stores
        if (tl + 1 < Tc) {
            prefetch(xga, tl + 2);
            step_body(tl + 1, 1, xgb);
            lds_barrier();
        }
    }
}

// ---------------------------------------------------------------------------
// Split-bf16 MFMA GEMM (R8-verified): C = A @ Bw^T + (bi+bh).
// ---------------------------------------------------------------------------
template<int KP, bool SLICED>
__global__ __launch_bounds__(256)
void gemm_mfma(const float* __restrict__ A,
               const float* __restrict__ Bw,
               const float* __restrict__ bi, const float* __restrict__ bh,
               float* __restrict__ C, int t0, int tcShift)
{
    constexpr int K = KP * 32;
    __shared__ __align__(16) unsigned short Ah[4][128][8], Al[4][128][8];
    __shared__ __align__(16) unsigned short Bh[4][64][8],  Bl[4][64][8];
    const int tid  = threadIdx.x;
    const int n0   = blockIdx.x * 64;
    const int m0   = blockIdx.y * 128;
    const int wv   = tid >> 6;
    const int lane = tid & 63;
    const int quad = lane >> 4, ml = lane & 15;

    f32x4 acc[2][4] = {};
    float bias[4];
#pragma unroll
    for (int nt = 0; nt < 4; ++nt) {
        int n = n0 + nt * 16 + ml;
        bias[nt] = bi[n] + bh[n];
    }

    for (int kp = 0; kp < KP; ++kp) {
        if (kp) __syncthreads();
#pragma unroll
        for (int r = 0; r < 2; ++r) {
            int u = tid + 256 * r;
            int m = u >> 2, ck = u & 3;
            size_t abase;
            if (SLICED) {
                int mg = m0 + m;
                int b  = mg >> tcShift, tl = mg & ((1 << tcShift) - 1);
                abase = ((size_t)b * NT + (t0 + tl)) * K;
            } else {
                abase = (size_t)(m0 + m) * K;
            }
            const float* s = A + abase + kp * 32 + ck * 8;
            float4 v0 = *(const float4*)s;
            float4 v1 = *(const float4*)(s + 4);
            uint4 H, L;
            split2(v0.x, v0.y, H.x, L.x); split2(v0.z, v0.w, H.y, L.y);
            split2(v1.x, v1.y, H.z, L.z); split2(v1.z, v1.w, H.w, L.w);
            *(uint4*)&Ah[ck][m][0] = H;
            *(uint4*)&Al[ck][m][0] = L;
        }
        {
            int n = tid >> 2, ck = tid & 3;
            const float* s = Bw + (size_t)(n0 + n) * K + kp * 32 + ck * 8;
            float4 v0 = *(const float4*)s;
            float4 v1 = *(const float4*)(s + 4);
            uint4 H, L;
            split2(v0.x, v0.y, H.x, L.x); split2(v0.z, v0.w, H.y, L.y);
            split2(v1.x, v1.y, H.z, L.z); split2(v1.z, v1.w, H.w, L.w);
            *(uint4*)&Bh[ck][n][0] = H;
            *(uint4*)&Bl[ck][n][0] = L;
        }
        __syncthreads();

        bf16x8 ah0 = *(const bf16x8*)&Ah[quad][(2 * wv + 0) * 16 + ml][0];
        bf16x8 al0 = *(const bf16x8*)&Al[quad][(2 * wv + 0) * 16 + ml][0];
        bf16x8 ah1 = *(const bf16x8*)&Ah[quad][(2 * wv + 1) * 16 + ml][0];
        bf16x8 al1 = *(const bf16x8*)&Al[quad][(2 * wv + 1) * 16 + ml][0];
#pragma unroll
        for (int nt = 0; nt < 4; ++nt) {
            bf16x8 bhv = *(const bf16x8*)&Bh[quad][nt * 16 + ml][0];
            bf16x8 blv = *(const bf16x8*)&Bl[quad][nt * 16 + ml][0];
            MFMA16(acc[0][nt], ah0, bhv);
            MFMA16(acc[0][nt], ah0, blv);
            MFMA16(acc[0][nt], al0, bhv);
            MFMA16(acc[1][nt], ah1, bhv);
            MFMA16(acc[1][nt], ah1, blv);
            MFMA16(acc[1][nt], al1, bhv);
        }
    }

#pragma unroll
    for (int mt = 0; mt < 2; ++mt)
#pragma unroll
        for (int nt = 0; nt < 4; ++nt)
#pragma unroll
            for (int reg = 0; reg < 4; ++reg) {
                int m = m0 + (2 * wv + mt) * 16 + quad * 4 + reg;
                int n = n0 + nt * 16 + ml;
                C[(size_t)m * NG + n] = acc[mt][nt][reg] + bias[nt];
            }
}

// ---------------------------------------------------------------------------
// out[b] = fc2_w . relu(fc1_w @ h1_last[b] + fc1_b) + fc2_b
// ---------------------------------------------------------------------------
__global__ void fc_head(const float* __restrict__ h1,
                        const float* __restrict__ fc1w, const float* __restrict__ fc1b,
                        const float* __restrict__ fc2w, const float* __restrict__ fc2b,
                        float* __restrict__ out)
{
    int b = blockIdx.x, j = threadIdx.x;
    const float4* wr = (const float4*)(fc1w + (size_t)j * NH);
    const float4* hv = (const float4*)(h1 + (size_t)b * NH);
    float acc = fc1b[j];
#pragma unroll
    for (int q = 0; q < 32; ++q) {
        float4 w = wr[q], h = hv[q];
        acc += w.x * h.x + w.y * h.y + w.z * h.z + w.w * h.w;
    }
    float z = fmaxf(acc, 0.0f);
    float p = fc2w[j] * z;
#pragma unroll
    for (int off = 32; off > 0; off >>= 1) p += __shfl_down(p, off);
    if (j == 0) out[b] = p + fc2b[0];
}

extern "C" void kernel_launch(void* const* d_in, const int* in_sizes, int n_in,
                              void* d_out, int out_size, void* d_ws, size_t ws_size,
                              hipStream_t stream)
{
    const float* x     = (const float*)d_in[0];
    const float* w_ih0 = (const float*)d_in[1];
    const float* w_hh0 = (const float*)d_in[2];
    const float* b_ih0 = (const float*)d_in[3];
    const float* b_hh0 = (const float*)d_in[4];
    const float* w_ih1 = (const float*)d_in[5];
    const float* w_hh1 = (const float*)d_in[6];
    const float* b_ih1 = (const float*)d_in[7];
    const float* b_hh1 = (const float*)d_in[8];
    const float* fc1w  = (const float*)d_in[9];
    const float* fc1b  = (const float*)d_in[10];
    const float* fc2w  = (const float*)d_in[11];
    const float* fc2b  = (const float*)d_in[12];
    float* out = (float*)d_out;
    float* ws  = (float*)d_ws;

    // xg0 + xg1 + h0 + 4 state arrays (Tc=64 at the known ws budget)
    int Tc = 1;
    for (int cand = 256; cand >= 1; cand >>= 1) {
        size_t need = 4ull * ((size_t)NB * cand * (2 * NG + NH) + 4ull * NB * NH);
        if (need <= ws_size) { Tc = cand; break; }
    }
    int tcShift = __builtin_ctz((unsigned)Tc);

    size_t o_xg0 = 0;
    size_t o_xg1 = o_xg0 + (size_t)NB * Tc * NG;
    size_t o_h0  = o_xg1 + (size_t)NB * Tc * NG;
    size_t o_h0s = o_h0  + (size_t)NB * Tc * NH;
    size_t o_c0s = o_h0s + (size_t)NB * NH;
    size_t o_h1s = o_c0s + (size_t)NB * NH;
    size_t o_c1s = o_h1s + (size_t)NB * NH;

    const int M = NB * Tc;
    const int nchunk = NT / Tc;

    // xg0 for chunk 0
    gemm_mfma<1, true><<<dim3(8, M / 128), 256, 0, stream>>>(
        x, w_ih0, b_ih0, b_hh0, ws + o_xg0, 0, tcShift);

    for (int i = 0; i <= nchunk; ++i) {
        int doA = (i < nchunk), doB = (i >= 1);
        recur_pair<<<64, 512, 0, stream>>>(
            ws + o_xg0, ws + o_xg1, w_hh0, w_hh1, ws + o_h0,
            ws + o_h0s, ws + o_c0s, ws + o_h1s, ws + o_c1s,
            Tc, doA, doB, i == 0, i == 1);
        if (i < nchunk)        // xg1 for chunk i (consumed by role1 next iter)
            gemm_mfma<4, false><<<dim3(8, M / 128), 256, 0, stream>>>(
                ws + o_h0, w_ih1, b_ih1, b_hh1, ws + o_xg1, 0, 0);
        if (i + 1 < nchunk)    // xg0 for chunk i+1 (consumed by role0 next iter)
            gemm_mfma<1, true><<<dim3(8, M / 128), 256, 0, stream>>>(
                x, w_ih0, b_ih0, b_hh0, ws + o_xg0, (i + 1) * Tc, tcShift);
    }
    fc_head<<<NB, 64, 0, stream>>>(ws + o_h1s, fc1w, fc1b, fc2w, fc2b, out);
}